// Round 10
// baseline (572.931 us; speedup 1.0000x reference)
//
#include <hip/hip_runtime.h>

typedef long long i64;
typedef unsigned short u16;
typedef __attribute__((ext_vector_type(8))) short short8;
typedef __attribute__((ext_vector_type(4))) float f32x4;

#define Bv 8
#define Nv 1024
#define Dv 768
#define Hh 4
#define DKv 192
#define BND ((i64)Bv * Nv * Dv)      /* 6,291,456  */
#define HBND ((i64)Hh * BND)         /* 25,165,824 */

__device__ __forceinline__ u16 f2bf(float f) {
    unsigned u = __builtin_bit_cast(unsigned, f);
    u += 0x7fffu + ((u >> 16) & 1u);
    return (u16)(u >> 16);
}
__device__ __forceinline__ float bf2f(u16 h) {
    unsigned u = ((unsigned)h) << 16;
    return __builtin_bit_cast(float, u);
}

// async global->LDS, 16B per lane. LDS dest must be wave-uniform base.
__device__ __forceinline__ void gl_lds16(const u16* g, u16* l) {
    __builtin_amdgcn_global_load_lds(
        (const __attribute__((address_space(1))) void*)g,
        (__attribute__((address_space(3))) void*)l, 16, 0, 0);
}

// ---------------------------------------------------------------------------
// bf16 MFMA GEMM:  C[z] = epilogue( A[z] (MxK) @ Bt[z]^T (NxK) + bias[z] )
// 128x128 tile, BK=64, 256 threads (4 waves, 64x64 sub-tile each).
// Swapped mfma operand order (first operand = Bt rows) -> C/D reg dim runs
// along contiguous n -> vector epilogue. XOR slot swizzle both sides.
// 1D launch + XCD-chunked swizzle: L = (bid&7)*(grid/8) + (bid>>3);
// ORD 0: bn = L%NBN, bm = (L/NBN)%NBM, z = L/(NBN*NBM)   (bn fastest, z slow)
// ORD 1: bn = L%NBN, z  = (L/NBN)%NZ,  bm = L/(NBN*NZ)   (bm slowest)
// EPI: 0 = f32 store (+bias), 1 = bf16 store (+bias),
//      2 = X-update: X = bf16( bf2f(X) + relu(acc + bias) )  (u16*, RMW)
// CATK: A is X in (h,BN,768) layout; logical k = h*768 + d (cat view).
// bias2: if non-null, z >= NZ/2 uses bias2[z - NZ/2] (fused q/k dispatch).
// zmaskBt: Bt batch offset uses (z & zmaskBt) (shared-Bt indexing).
// ---------------------------------------------------------------------------
template <int EPI, bool CATK, int ORD, int NBN, int NBM, int NZ>
__global__ __launch_bounds__(256) void gemm_bf16(
    const u16* __restrict__ A, i64 sA, int lda,
    const u16* __restrict__ Bt, i64 sBt, int ldbt, int zmaskBt,
    const float* __restrict__ bias, i64 sBias, const float* __restrict__ bias2,
    void* __restrict__ Cv, i64 sC, int ldc, int K, int koff)
{
    __shared__ u16 Asb[128 * 64];
    __shared__ u16 Bsb[128 * 64];

    const int L = (blockIdx.x & 7) * ((NBN * NBM * NZ) >> 3) + (blockIdx.x >> 3);
    int bn, bm, z;
    if (ORD == 0) {
        bn = L % NBN; const int t2 = L / NBN; bm = t2 % NBM; z = t2 / NBM;
    } else {
        bn = L % NBN; const int t2 = L / NBN; z = t2 % NZ; bm = t2 / NZ;
    }

    A  += (i64)z * sA;
    Bt += (i64)(z & zmaskBt) * sBt;
    const float* bp = bias;
    int zb = z;
    if (bias2 != nullptr && z >= NZ / 2) { bp = bias2; zb = z - NZ / 2; }
    if (bp) bp += (i64)zb * sBias;
    const int kb = z * koff;

    const int bmp = bm * 128, bnp = bn * 128;
    const int tid = threadIdx.x;
    const int w = tid >> 6, l = tid & 63;
    const int wr = w >> 1, wc = w & 1;
    const int kgrp = l >> 4, lr = l & 15;

    const u16* Ab = A + (i64)bmp * lda;
    const u16* Bb = Bt + (i64)bnp * ldbt;

    f32x4 acc[4][4];   // [i: n-frag (reg dim)][j: m-frag (lane dim)]
    #pragma unroll
    for (int i = 0; i < 4; ++i)
        #pragma unroll
        for (int j = 0; j < 4; ++j)
            acc[i][j] = (f32x4){0.f, 0.f, 0.f, 0.f};

    for (int k0i = 0; k0i < K; k0i += 64) {
        const int k0 = kb + k0i;
        if (k0i) __syncthreads();
        #pragma unroll
        for (int t = 0; t < 4; ++t) {
            const int idx = t * 256 + tid;
            const int r = idx >> 3, s = idx & 7;
            const int ss = s ^ (r & 7);
            const u16* src;
            if (CATK) {
                src = A + (i64)(k0 / Dv) * BND + (i64)(bmp + r) * Dv + (k0 % Dv) + ss * 8;
            } else {
                src = Ab + (i64)r * lda + k0 + ss * 8;
            }
            gl_lds16(src, &Asb[(t * 256 + w * 64) * 8]);
        }
        #pragma unroll
        for (int t = 0; t < 4; ++t) {
            const int idx = t * 256 + tid;
            const int r = idx >> 3, s = idx & 7;
            const int ss = s ^ (r & 7);
            gl_lds16(Bb + (i64)r * ldbt + k0 + ss * 8, &Bsb[(t * 256 + w * 64) * 8]);
        }
        __syncthreads();

        #pragma unroll
        for (int ks = 0; ks < 2; ++ks) {
            const int slot = ks * 4 + kgrp;
            short8 a[4], b[4];
            #pragma unroll
            for (int i = 0; i < 4; ++i) {          // Bt rows (n side)
                const int r = wc * 64 + i * 16 + lr;
                a[i] = *(const short8*)&Bsb[r * 64 + ((slot ^ (r & 7)) << 3)];
            }
            #pragma unroll
            for (int j = 0; j < 4; ++j) {          // A rows (m side)
                const int r = wr * 64 + j * 16 + lr;
                b[j] = *(const short8*)&Asb[r * 64 + ((slot ^ (r & 7)) << 3)];
            }
            #pragma unroll
            for (int i = 0; i < 4; ++i)
                #pragma unroll
                for (int j = 0; j < 4; ++j)
                    acc[i][j] = __builtin_amdgcn_mfma_f32_16x16x32_bf16(
                        a[i], b[j], acc[i][j], 0, 0, 0);
        }
    }

    f32x4 bj[4];
    #pragma unroll
    for (int i = 0; i < 4; ++i) {
        const int nb = bnp + wc * 64 + i * 16 + kgrp * 4;
        bj[i] = bp ? *(const f32x4*)&bp[nb] : (f32x4){0.f, 0.f, 0.f, 0.f};
    }

    #pragma unroll
    for (int j = 0; j < 4; ++j) {
        const int m = bmp + wr * 64 + j * 16 + lr;
        #pragma unroll
        for (int i = 0; i < 4; ++i) {
            const int nb = bnp + wc * 64 + i * 16 + kgrp * 4;
            const i64 off = (i64)z * sC + (i64)m * ldc + nb;
            f32x4 v = acc[i][j] + bj[i];
            if (EPI == 0) {
                *(f32x4*)&((float*)Cv)[off] = v;
            } else if (EPI == 1) {
                ushort4 o;
                o.x = f2bf(v[0]); o.y = f2bf(v[1]);
                o.z = f2bf(v[2]); o.w = f2bf(v[3]);
                *(ushort4*)&((u16*)Cv)[off] = o;
            } else {
                u16* xp = (u16*)Cv + off;
                ushort4 old = *(const ushort4*)xp;
                ushort4 o;
                o.x = f2bf(bf2f(old.x) + fmaxf(v[0], 0.f));
                o.y = f2bf(bf2f(old.y) + fmaxf(v[1], 0.f));
                o.z = f2bf(bf2f(old.z) + fmaxf(v[2], 0.f));
                o.w = f2bf(bf2f(old.w) + fmaxf(v[3], 0.f));
                *(ushort4*)xp = o;
            }
        }
    }
}

// ---------------------------------------------------------------------------
// Fused 3-edge masked scores, 128x128 tile, 256 threads — identical loop
// structure to gemm_bf16 (the proven ~790 TF config, 84 VGPR / 3 blocks/CU).
// NO persistent fin registers: edges run sequentially reusing ONE acc[4][4];
// after edge e's K-loop the tile is committed via predicated stores:
//   e==0: full ushort4 store, (adj==1 && s!=0) ? s : -1e9   (placeholder for
//         adj==2/3, overwritten below; adj==0 keeps -1e9 — exact semantics)
//   e>0 : exec-masked scalar u16 stores where adj==e+1 (s==0 -> -1e9)
// Each element matches <=1 edge and is owned by one thread -> program-order
// correct. adj re-read from L2 per edge (trades 16 VGPR for cached loads).
// Grid 2048: b = bid&7 (XCD pin), h fastest, then 8x8 tiles of 128.
// ---------------------------------------------------------------------------
__global__ __launch_bounds__(256) void scores_mfma(
    const u16* __restrict__ qb, const u16* __restrict__ kb,
    const int* __restrict__ adj, u16* __restrict__ sb)
{
    __shared__ u16 Qs[128 * 64];
    __shared__ u16 Ks[128 * 64];

    const int bid = blockIdx.x;
    const int b = bid & 7;
    const int t2 = bid >> 3;          // [0,256)
    const int h = t2 & 3;
    const int tile = t2 >> 2;         // [0,64)
    const int mt = tile & 7, nt = tile >> 3;
    const int m0 = mt * 128, n0 = nt * 128;
    const int zga = h * 8 + b;

    const int tid = threadIdx.x;
    const int w = tid >> 6, l = tid & 63;
    const int wr = w >> 1, wc = w & 1;   // wr: n-half, wc: m-half
    const int kgrp = l >> 4, lr = l & 15;

    const u16* qbase = qb + ((i64)b * Nv + n0) * Dv + h * DKv;
    const u16* kbase = kb + ((i64)b * Nv + m0) * Dv + h * DKv;

    const float scale = 0.07216878364870323f;  // 1/sqrt(192)

    for (int e = 0; e < 3; ++e) {
        const u16* qe = qbase + (i64)e * BND;
        const u16* ke = kbase + (i64)e * BND;

        f32x4 acc[4][4];   // [i: m-frag (reg dim)][j: n-frag (lane dim)]
        #pragma unroll
        for (int i = 0; i < 4; ++i)
            #pragma unroll
            for (int j = 0; j < 4; ++j)
                acc[i][j] = (f32x4){0.f, 0.f, 0.f, 0.f};

        for (int k0 = 0; k0 < DKv; k0 += 64) {
            __syncthreads();   // protect LDS vs previous phase's readers
            #pragma unroll
            for (int t = 0; t < 4; ++t) {
                const int idx = t * 256 + tid;
                const int r = idx >> 3, s = idx & 7;
                const int ss = s ^ (r & 7);
                gl_lds16(qe + (i64)r * Dv + k0 + ss * 8, &Qs[(t * 256 + w * 64) * 8]);
            }
            #pragma unroll
            for (int t = 0; t < 4; ++t) {
                const int idx = t * 256 + tid;
                const int r = idx >> 3, s = idx & 7;
                const int ss = s ^ (r & 7);
                gl_lds16(ke + (i64)r * Dv + k0 + ss * 8, &Ks[(t * 256 + w * 64) * 8]);
            }
            __syncthreads();

            #pragma unroll
            for (int ks = 0; ks < 2; ++ks) {
                const int slot = ks * 4 + kgrp;
                short8 a[4], bq2[4];
                #pragma unroll
                for (int i = 0; i < 4; ++i) {          // K rows (m side, reg dim)
                    const int r = wc * 64 + i * 16 + lr;
                    a[i] = *(const short8*)&Ks[r * 64 + ((slot ^ (r & 7)) << 3)];
                }
                #pragma unroll
                for (int j = 0; j < 4; ++j) {          // Q rows (n side, lane dim)
                    const int r = wr * 64 + j * 16 + lr;
                    bq2[j] = *(const short8*)&Qs[r * 64 + ((slot ^ (r & 7)) << 3)];
                }
                #pragma unroll
                for (int i = 0; i < 4; ++i)
                    #pragma unroll
                    for (int j = 0; j < 4; ++j)
                        acc[i][j] = __builtin_amdgcn_mfma_f32_16x16x32_bf16(
                            a[i], bq2[j], acc[i][j], 0, 0, 0);
            }
        }

        // commit edge e via predicated stores (no persistent fin registers)
        #pragma unroll
        for (int i = 0; i < 4; ++i) {
            const int mb = m0 + wc * 64 + i * 16 + kgrp * 4;
            #pragma unroll
            for (int j = 0; j < 4; ++j) {
                const int n = n0 + wr * 64 + j * 16 + lr;
                const int4 av = *(const int4*)&adj[((i64)b * Nv + n) * Nv + mb];
                const int avv[4] = {av.x, av.y, av.z, av.w};
                u16* sp = &sb[((i64)zga * Nv + n) * Nv + mb];
                if (e == 0) {
                    ushort4 o;
                    #pragma unroll
                    for (int rg = 0; rg < 4; ++rg) {
                        float f = acc[i][j][rg] * scale;
                        if (f == 0.f || avv[rg] != 1) f = -1e9f;
                        ((u16*)&o)[rg] = f2bf(f);
                    }
                    *(ushort4*)sp = o;
                } else {
                    #pragma unroll
                    for (int rg = 0; rg < 4; ++rg) {
                        if (avv[rg] == e + 1) {
                            float f = acc[i][j][rg] * scale;
                            if (f == 0.f) f = -1e9f;
                            sp[rg] = f2bf(f);
                        }
                    }
                }
            }
        }
    }
}

// row softmax over 1024 cols: read S bf16, write ga f32 (output) + P bf16
__global__ __launch_bounds__(256) void softmax_k(const u16* __restrict__ sb,
                                                 float* __restrict__ ga,
                                                 u16* __restrict__ gab)
{
    const i64 row = blockIdx.x;
    const int tid = threadIdx.x;
    const int wid = tid >> 6, lane = tid & 63;

    ushort4 sv = *(const ushort4*)&sb[row * (i64)Nv + tid * 4];
    float4 v;
    v.x = bf2f(sv.x); v.y = bf2f(sv.y); v.z = bf2f(sv.z); v.w = bf2f(sv.w);

    float m = fmaxf(fmaxf(v.x, v.y), fmaxf(v.z, v.w));
    #pragma unroll
    for (int o = 32; o >= 1; o >>= 1) m = fmaxf(m, __shfl_xor(m, o));

    __shared__ float red[4];
    if (lane == 0) red[wid] = m;
    __syncthreads();
    m = fmaxf(fmaxf(red[0], red[1]), fmaxf(red[2], red[3]));

    float e0 = expf(v.x - m), e1 = expf(v.y - m), e2 = expf(v.z - m), e3 = expf(v.w - m);
    float s = e0 + e1 + e2 + e3;
    #pragma unroll
    for (int o = 32; o >= 1; o >>= 1) s += __shfl_xor(s, o);
    __syncthreads();
    if (lane == 0) red[wid] = s;
    __syncthreads();
    s = red[0] + red[1] + red[2] + red[3];

    const float inv = 1.0f / s;
    float4 o;
    o.x = e0 * inv; o.y = e1 * inv; o.z = e2 * inv; o.w = e3 * inv;
    *(float4*)&ga[row * (i64)Nv + tid * 4] = o;

    ushort4 ob;
    ob.x = f2bf(o.x); ob.y = f2bf(o.y); ob.z = f2bf(o.z); ob.w = f2bf(o.w);
    *(ushort4*)&gab[row * (i64)Nv + tid * 4] = ob;
}

// nodes f32 -> nodesb bf16 + X broadcast x4 (one read, five writes)
__global__ __launch_bounds__(256) void prep_k(const float* __restrict__ nodes,
                                              u16* __restrict__ nodesb,
                                              u16* __restrict__ Xb)
{
    const i64 i = (i64)blockIdx.x * 256 + threadIdx.x;  // over BND/4
    float4 v = ((const float4*)nodes)[i];
    ushort4 o;
    o.x = f2bf(v.x); o.y = f2bf(v.y); o.z = f2bf(v.z); o.w = f2bf(v.w);
    ((ushort4*)nodesb)[i] = o;
    const i64 q4 = BND / 4;
    #pragma unroll
    for (int h = 0; h < Hh; ++h) ((ushort4*)Xb)[(i64)h * q4 + i] = o;
}

// all weight transposes in one dispatch. z<3: Wq[e]; 3..5: Wk[e]; 6,7: gcnW;
// 8..11: Wagg 768-row slice. All 768x768 transposes.
__global__ __launch_bounds__(256) void trans_all(
    const float* __restrict__ Wq, const float* __restrict__ Wk,
    const float* __restrict__ gcnW, const float* __restrict__ Wagg,
    u16* __restrict__ wqkt, u16* __restrict__ gcnWt, u16* __restrict__ waggt)
{
    const int z = blockIdx.z;
    const i64 W768 = (i64)768 * 768;
    const float* src;
    u16* dst;
    int ldo;
    if (z < 3)      { src = Wq + z * W768;        dst = wqkt + z * W768;          ldo = 768; }
    else if (z < 6) { src = Wk + (z - 3) * W768;  dst = wqkt + (i64)z * W768;     ldo = 768; }
    else if (z < 8) { src = gcnW + (z - 6) * W768; dst = gcnWt + (i64)(z - 6) * W768; ldo = 768; }
    else            { src = Wagg + (i64)(z - 8) * W768; dst = waggt + (i64)(z - 8) * 768; ldo = 3072; }

    __shared__ u16 t[32][33];
    const int c0 = blockIdx.x * 32, r0 = blockIdx.y * 32;
    const int tx = threadIdx.x & 31, ty = threadIdx.x >> 5;
    #pragma unroll
    for (int i = ty; i < 32; i += 8)
        t[i][tx] = f2bf(src[(i64)(r0 + i) * 768 + c0 + tx]);
    __syncthreads();
    #pragma unroll
    for (int i = ty; i < 32; i += 8)
        dst[(i64)(c0 + i) * ldo + r0 + tx] = t[tx][i];
}

// out = p0 + p1 + bias (split-K reduce), float4 per thread
__global__ __launch_bounds__(256) void addbias_k(
    const float* __restrict__ p0, const float* __restrict__ p1,
    const float* __restrict__ bias, float* __restrict__ out)
{
    const i64 i4 = (i64)blockIdx.x * 256 + threadIdx.x;  // over BND/4
    const int nb = (int)((i4 * 4) % Dv);
    float4 a = ((const float4*)p0)[i4];
    float4 b = ((const float4*)p1)[i4];
    float4 bv = *(const float4*)&bias[nb];
    float4 o;
    o.x = a.x + b.x + bv.x; o.y = a.y + b.y + bv.y;
    o.z = a.z + b.z + bv.z; o.w = a.w + b.w + bv.w;
    ((float4*)out)[i4] = o;
}

// ---------------------------------------------------------------------------
extern "C" void kernel_launch(void* const* d_in, const int* in_sizes, int n_in,
                              void* d_out, int out_size, void* d_ws, size_t ws_size,
                              hipStream_t stream)
{
    const float* nodes = (const float*)d_in[0];
    const int*   adj   = (const int*)d_in[1];
    const float* Wq    = (const float*)d_in[2];
    const float* bq    = (const float*)d_in[3];
    const float* Wk    = (const float*)d_in[4];
    const float* bk    = (const float*)d_in[5];
    const float* gcnW  = (const float*)d_in[6];
    const float* gcnb  = (const float*)d_in[7];
    const float* Wagg  = (const float*)d_in[8];
    const float* bagg  = (const float*)d_in[9];

    float* out = (float*)d_out;             // (B,N,D) f32
    float* gaf = out + BND;                 // (H,B,N,N) f32

    const i64 W768 = (i64)768 * 768;
    const i64 HTZ  = (i64)768 * 1024;       // per-z H^T slab (d-major, 1024 cols)
    u16* ws     = (u16*)d_ws;
    u16* qb     = ws;                       // 3*BND           (phase 1)
    u16* kb2    = ws + 3 * BND;             // 3*BND           (phase 1)
    u16* gab    = ws;                       // HBND bf16       (alias after scores)
    u16* nodesb = ws + 6 * BND;             // BND
    u16* gcnWt  = nodesb + BND;             // 2*W768
    u16* waggt  = gcnWt + 2 * W768;         // 4*W768
    u16* Xb     = waggt + 4 * W768;         // HBND
    u16* Htz    = Xb + HBND;                // 32*HTZ == HBND, time-shared:
    u16* wqkt   = Htz;                      //   6*W768 (dead after q/k proj)
    u16* sbuf   = Htz;                      //   HBND (S bf16; dead after softmax)
    float* part = (float*)Htz;              //   2*BND f32 (final split-K)

    dim3 blk(256);

    prep_k<<<dim3((unsigned)(BND / 4 / 256)), blk, 0, stream>>>(nodes, nodesb, Xb);
    trans_all<<<dim3(24, 24, 12), blk, 0, stream>>>(Wq, Wk, gcnW, Wagg, wqkt, gcnWt, waggt);

    // fused q/k projections: z 0..2 -> q (bias bq), z 3..5 -> k (bias bk)
    gemm_bf16<1, false, 1, 6, 64, 6><<<dim3(2304), blk, 0, stream>>>(
        nodesb, 0, Dv, wqkt, W768, Dv, -1, bq, Dv, bk, qb, BND, Dv, Dv, 0);

    // fused masked scores -> S bf16 (128x128 tiles, predicated-store edges)
    scores_mfma<<<dim3(2048), blk, 0, stream>>>(qb, kb2, adj, sbuf);

    // softmax: ga f32 (output) + P bf16 (gab aliases q/k, both dead now)
    softmax_k<<<dim3(Hh * Bv * Nv), blk, 0, stream>>>(sbuf, gaf, gab);

    for (int it = 0; it < 2; ++it) {
        if (it == 0) {
            // iter 0: X identical across heads -> per-b H0^T = gcnW[0]^T @ nodes[b]^T
            // Htz[b] is [768][1024] contiguous; Xupd indexes it by z&7.
            gemm_bf16<1, false, 0, 8, 6, 8><<<dim3(384), blk, 0, stream>>>(
                gcnWt, 0, Dv, nodesb, (i64)Nv * Dv, Dv, 7, nullptr, 0, nullptr,
                Htz, HTZ, 1024, Dv, 0);
            gemm_bf16<2, false, 0, 6, 8, 32><<<dim3(1536), blk, 0, stream>>>(
                gab, (i64)Nv * Nv, Nv, Htz, HTZ, 1024, 7, gcnb, 0, nullptr,
                Xb, (i64)Nv * Dv, Dv, Nv, 0);
        } else {
            // iter 1: per-z H^T = gcnW[1]^T @ X[z]^T, Htz[z] = [768][1024]
            gemm_bf16<1, false, 0, 8, 6, 32><<<dim3(1536), blk, 0, stream>>>(
                gcnWt + W768, 0, Dv, Xb, (i64)Nv * Dv, Dv, 31, nullptr, 0, nullptr,
                Htz, HTZ, 1024, Dv, 0);
            gemm_bf16<2, false, 0, 6, 8, 32><<<dim3(1536), blk, 0, stream>>>(
                gab, (i64)Nv * Nv, Nv, Htz, HTZ, 1024, 31, gcnb + (i64)Dv, 0, nullptr,
                Xb, (i64)Nv * Dv, Dv, Nv, 0);
        }
    }

    // final: out = cat(X) @ W_agg + b_agg, split-K x2 into f32 partials
    gemm_bf16<0, true, 0, 6, 64, 2><<<dim3(768), blk, 0, stream>>>(
        Xb, 0, Dv, waggt, 0, Hh * Dv, -1, nullptr, 0, nullptr,
        part, BND, Dv, (Hh * Dv) / 2, (Hh * Dv) / 2);

    addbias_k<<<dim3((unsigned)(BND / 4 / 256)), blk, 0, stream>>>(
        part, part + BND, bagg, out);
}

// Round 11
// 566.729 us; speedup vs baseline: 1.0109x; 1.0109x over previous
//
#include <hip/hip_runtime.h>

typedef long long i64;
typedef unsigned short u16;
typedef __attribute__((ext_vector_type(8))) short short8;
typedef __attribute__((ext_vector_type(4))) float f32x4;

#define Bv 8
#define Nv 1024
#define Dv 768
#define Hh 4
#define DKv 192
#define BND ((i64)Bv * Nv * Dv)      /* 6,291,456  */
#define HBND ((i64)Hh * BND)         /* 25,165,824 */

__device__ __forceinline__ u16 f2bf(float f) {
    unsigned u = __builtin_bit_cast(unsigned, f);
    u += 0x7fffu + ((u >> 16) & 1u);
    return (u16)(u >> 16);
}
__device__ __forceinline__ float bf2f(u16 h) {
    unsigned u = ((unsigned)h) << 16;
    return __builtin_bit_cast(float, u);
}

// async global->LDS, 16B per lane. LDS dest must be wave-uniform base.
__device__ __forceinline__ void gl_lds16(const u16* g, u16* l) {
    __builtin_amdgcn_global_load_lds(
        (const __attribute__((address_space(1))) void*)g,
        (__attribute__((address_space(3))) void*)l, 16, 0, 0);
}

#define VMCNT(n) asm volatile("s_waitcnt vmcnt(" #n ")" ::: "memory")

// ---------------------------------------------------------------------------
// bf16 MFMA GEMM (m97-structure): 128x128 tile, BK=64, 256 threads.
// (unchanged from round 7 — see comments there)
// ---------------------------------------------------------------------------
template <int EPI, bool CATK, int ORD, int NBN, int NBM, int NZ>
__global__ __launch_bounds__(256) void gemm_bf16(
    const u16* __restrict__ A, i64 sA, int lda,
    const u16* __restrict__ Bt, i64 sBt, int ldbt, int zmaskBt,
    const float* __restrict__ bias, i64 sBias, const float* __restrict__ bias2,
    void* __restrict__ Cv, i64 sC, int ldc, int K, int koff)
{
    __shared__ u16 Asb[128 * 64];
    __shared__ u16 Bsb[128 * 64];

    const int L = (blockIdx.x & 7) * ((NBN * NBM * NZ) >> 3) + (blockIdx.x >> 3);
    int bn, bm, z;
    if (ORD == 0) {
        bn = L % NBN; const int t2 = L / NBN; bm = t2 % NBM; z = t2 / NBM;
    } else {
        bn = L % NBN; const int t2 = L / NBN; z = t2 % NZ; bm = t2 / NZ;
    }

    A  += (i64)z * sA;
    Bt += (i64)(z & zmaskBt) * sBt;
    const float* bp = bias;
    int zb = z;
    if (bias2 != nullptr && z >= NZ / 2) { bp = bias2; zb = z - NZ / 2; }
    if (bp) bp += (i64)zb * sBias;
    const int kb = z * koff;

    const int bmp = bm * 128, bnp = bn * 128;
    const int tid = threadIdx.x;
    const int w = tid >> 6, l = tid & 63;
    const int wr = w >> 1, wc = w & 1;
    const int kgrp = l >> 4, lr = l & 15;

    const u16* Ab = A + (i64)bmp * lda;
    const u16* Bb = Bt + (i64)bnp * ldbt;

    f32x4 acc[4][4];
    #pragma unroll
    for (int i = 0; i < 4; ++i)
        #pragma unroll
        for (int j = 0; j < 4; ++j)
            acc[i][j] = (f32x4){0.f, 0.f, 0.f, 0.f};

    for (int k0i = 0; k0i < K; k0i += 64) {
        const int k0 = kb + k0i;
        if (k0i) __syncthreads();
        #pragma unroll
        for (int t = 0; t < 4; ++t) {
            const int idx = t * 256 + tid;
            const int r = idx >> 3, s = idx & 7;
            const int ss = s ^ (r & 7);
            const u16* src;
            if (CATK) {
                src = A + (i64)(k0 / Dv) * BND + (i64)(bmp + r) * Dv + (k0 % Dv) + ss * 8;
            } else {
                src = Ab + (i64)r * lda + k0 + ss * 8;
            }
            gl_lds16(src, &Asb[(t * 256 + w * 64) * 8]);
        }
        #pragma unroll
        for (int t = 0; t < 4; ++t) {
            const int idx = t * 256 + tid;
            const int r = idx >> 3, s = idx & 7;
            const int ss = s ^ (r & 7);
            gl_lds16(Bb + (i64)r * ldbt + k0 + ss * 8, &Bsb[(t * 256 + w * 64) * 8]);
        }
        __syncthreads();

        #pragma unroll
        for (int ks = 0; ks < 2; ++ks) {
            const int slot = ks * 4 + kgrp;
            short8 a[4], b[4];
            #pragma unroll
            for (int i = 0; i < 4; ++i) {
                const int r = wc * 64 + i * 16 + lr;
                a[i] = *(const short8*)&Bsb[r * 64 + ((slot ^ (r & 7)) << 3)];
            }
            #pragma unroll
            for (int j = 0; j < 4; ++j) {
                const int r = wr * 64 + j * 16 + lr;
                b[j] = *(const short8*)&Asb[r * 64 + ((slot ^ (r & 7)) << 3)];
            }
            #pragma unroll
            for (int i = 0; i < 4; ++i)
                #pragma unroll
                for (int j = 0; j < 4; ++j)
                    acc[i][j] = __builtin_amdgcn_mfma_f32_16x16x32_bf16(
                        a[i], b[j], acc[i][j], 0, 0, 0);
        }
    }

    f32x4 bj[4];
    #pragma unroll
    for (int i = 0; i < 4; ++i) {
        const int nb = bnp + wc * 64 + i * 16 + kgrp * 4;
        bj[i] = bp ? *(const f32x4*)&bp[nb] : (f32x4){0.f, 0.f, 0.f, 0.f};
    }

    #pragma unroll
    for (int j = 0; j < 4; ++j) {
        const int m = bmp + wr * 64 + j * 16 + lr;
        #pragma unroll
        for (int i = 0; i < 4; ++i) {
            const int nb = bnp + wc * 64 + i * 16 + kgrp * 4;
            const i64 off = (i64)z * sC + (i64)m * ldc + nb;
            f32x4 v = acc[i][j] + bj[i];
            if (EPI == 0) {
                *(f32x4*)&((float*)Cv)[off] = v;
            } else if (EPI == 1) {
                ushort4 o;
                o.x = f2bf(v[0]); o.y = f2bf(v[1]);
                o.z = f2bf(v[2]); o.w = f2bf(v[3]);
                *(ushort4*)&((u16*)Cv)[off] = o;
            } else {
                u16* xp = (u16*)Cv + off;
                ushort4 old = *(const ushort4*)xp;
                ushort4 o;
                o.x = f2bf(bf2f(old.x) + fmaxf(v[0], 0.f));
                o.y = f2bf(bf2f(old.y) + fmaxf(v[1], 0.f));
                o.z = f2bf(bf2f(old.z) + fmaxf(v[2], 0.f));
                o.w = f2bf(bf2f(old.w) + fmaxf(v[3], 0.f));
                *(ushort4*)xp = o;
            }
        }
    }
}

// ---------------------------------------------------------------------------
// 256x256-tile X-update GEMM, 512 thr / 8 waves, BK=64, double-buffered
// 128KB LDS, 4-phase counted-vmcnt schedule (T3+T4) + setprio (T5).
//   X[z] = bf16( X[z] + relu( A[z](1024x1024) @ Bt[z&zmask]^T(768r x 1024k)
//                             + bias ) )
// Wave (wr=w>>2, wc=w&3): output 128m x 64n. acc[8 m-frag][4 n-frag].
// Per K-tile per thread, 8 gl_lds16 issued in order {Bq0,Bq1|Bq2,Bq3|Ap0,Ap1|
// Ap2,Ap3} across 4 phases (A region p = rows {32p..+32}U{128+32p..+32},
// exactly the rows phase p's MFMA reads). Phase p waits vmcnt(3/4/5/6)
// steady-state (last tile: 3/2/1/0) -> data provably ready, never drains to 0
// mid-loop. b-frags pre-read once per tile (32 VGPR). One barrier per phase.
// ---------------------------------------------------------------------------
__global__ __launch_bounds__(512, 2) void gemm256_xupd(
    const u16* __restrict__ A, i64 sA, int lda,
    const u16* __restrict__ Bt, i64 sBt, int ldbt, int zmask,
    const float* __restrict__ bias,
    u16* __restrict__ X, i64 sX, int ldx, int K)
{
    __shared__ u16 Asb[2][256 * 64];   // 64 KB
    __shared__ u16 Bsb[2][256 * 64];   // 64 KB

    // grid 384 = 3 bn x 4 bm x 32 z, XCD-chunked (48 blocks = 4 z per XCD)
    const int L = (blockIdx.x & 7) * 48 + (blockIdx.x >> 3);
    const int bn = L % 3;
    const int t2 = L / 3;
    const int bm = t2 & 3;
    const int z  = t2 >> 2;

    const u16* Ab = A + (i64)z * sA + (i64)(bm * 256) * lda;
    const u16* Bb = Bt + (i64)(z & zmask) * sBt + (i64)(bn * 256) * ldbt;

    const int tid = threadIdx.x;
    const int w = tid >> 6, l = tid & 63;
    const int wr = w >> 2;            // m half (128 rows)
    const int wc = w & 3;             // n quarter (64 cols)
    const int kgrp = l >> 4, lr = l & 15;
    const int srow = tid >> 3;        // staging row-in-region 0..63
    const int scol = tid & 7;         // staging 16B slot 0..7

    f32x4 acc[8][4];
    #pragma unroll
    for (int f = 0; f < 8; ++f)
        #pragma unroll
        for (int g = 0; g < 4; ++g)
            acc[f][g] = (f32x4){0.f, 0.f, 0.f, 0.f};

    short8 bfr[4][2];   // b-frags for current tile, read once per tile

// stage B quarter q / A region p of k-chunk k0_ into buffer bb_
#define STG_B(bb_, k0_, q_) { \
    const int r_ = (q_) * 64 + srow; \
    const int ss_ = scol ^ (r_ & 7); \
    gl_lds16(Bb + (i64)r_ * ldbt + (k0_) + ss_ * 8, &Bsb[bb_][(r_ * 8 + scol) * 8]); }
#define STG_A(bb_, k0_, p_) { \
    const int r_ = (srow < 32) ? ((p_) * 32 + srow) : (128 + (p_) * 32 + (srow - 32)); \
    const int ss_ = scol ^ (r_ & 7); \
    gl_lds16(Ab + (i64)r_ * lda + (k0_) + ss_ * 8, &Asb[bb_][(r_ * 8 + scol) * 8]); }
#define STG_PH(P_, bb_, k0_) \
    if ((P_) == 0) { STG_B(bb_, k0_, 0) STG_B(bb_, k0_, 1) } \
    else if ((P_) == 1) { STG_B(bb_, k0_, 2) STG_B(bb_, k0_, 3) } \
    else if ((P_) == 2) { STG_A(bb_, k0_, 0) STG_A(bb_, k0_, 1) } \
    else { STG_A(bb_, k0_, 2) STG_A(bb_, k0_, 3) }

// one compute phase: wait, barrier, ds_read, (prefetch), MFMA x16
#define PHASE(P_, VMN_, cur_, DOPF_, nxt_, k0n_) { \
    VMCNT(VMN_); \
    __builtin_amdgcn_s_barrier(); \
    asm volatile("" ::: "memory"); \
    if ((P_) == 0) { \
        _Pragma("unroll") \
        for (int g = 0; g < 4; ++g) \
            _Pragma("unroll") \
            for (int ks = 0; ks < 2; ++ks) { \
                const int r_ = wc * 64 + g * 16 + lr; \
                const int sl_ = ks * 4 + kgrp; \
                bfr[g][ks] = *(const short8*)&Bsb[cur_][r_ * 64 + ((sl_ ^ (r_ & 7)) << 3)]; \
            } \
    } \
    short8 afr[2][2]; \
    _Pragma("unroll") \
    for (int i = 0; i < 2; ++i) \
        _Pragma("unroll") \
        for (int ks = 0; ks < 2; ++ks) { \
            const int r_ = wr * 128 + (2 * (P_) + i) * 16 + lr; \
            const int sl_ = ks * 4 + kgrp; \
            afr[i][ks] = *(const short8*)&Asb[cur_][r_ * 64 + ((sl_ ^ (r_ & 7)) << 3)]; \
        } \
    if (DOPF_) { STG_PH(P_, nxt_, k0n_) } \
    __builtin_amdgcn_s_setprio(1); \
    _Pragma("unroll") \
    for (int i = 0; i < 2; ++i) \
        _Pragma("unroll") \
        for (int g = 0; g < 4; ++g) \
            _Pragma("unroll") \
            for (int ks = 0; ks < 2; ++ks) \
                acc[2 * (P_) + i][g] = __builtin_amdgcn_mfma_f32_16x16x32_bf16( \
                    bfr[g][ks], afr[i][ks], acc[2 * (P_) + i][g], 0, 0, 0); \
    __builtin_amdgcn_s_setprio(0); }

    const int NT = K / 64;

    // prologue: stage tile 0 fully, drain once
    STG_PH(0, 0, 0) STG_PH(1, 0, 0) STG_PH(2, 0, 0) STG_PH(3, 0, 0)
    VMCNT(0);
    __builtin_amdgcn_s_barrier();
    asm volatile("" ::: "memory");

    // main loop: tiles 0..NT-2, each prefetches tile kt+1
    for (int kt = 0; kt < NT - 1; ++kt) {
        const int cur = kt & 1, nxt = cur ^ 1;
        const int k0n = (kt + 1) * 64;
        PHASE(0, 3, cur, 1, nxt, k0n)
        PHASE(1, 4, cur, 1, nxt, k0n)
        PHASE(2, 5, cur, 1, nxt, k0n)
        PHASE(3, 6, cur, 1, nxt, k0n)
    }
    // epilogue tile NT-1: no prefetch, counts drain 3/2/1/0
    {
        const int cur = (NT - 1) & 1;
        PHASE(0, 3, cur, 0, 0, 0)
        PHASE(1, 2, cur, 0, 0, 0)
        PHASE(2, 1, cur, 0, 0, 0)
        PHASE(3, 0, cur, 0, 0, 0)
    }
#undef PHASE
#undef STG_PH
#undef STG_A
#undef STG_B

    f32x4 bj[4];
    #pragma unroll
    for (int g = 0; g < 4; ++g) {
        const int n = bn * 256 + wc * 64 + g * 16 + kgrp * 4;
        bj[g] = *(const f32x4*)&bias[n];
    }

    #pragma unroll
    for (int f = 0; f < 8; ++f) {
        const int m = bm * 256 + wr * 128 + f * 16 + lr;
        #pragma unroll
        for (int g = 0; g < 4; ++g) {
            const int n = bn * 256 + wc * 64 + g * 16 + kgrp * 4;
            u16* xp = X + (i64)z * sX + (i64)m * ldx + n;
            f32x4 v = acc[f][g] + bj[g];
            ushort4 old = *(const ushort4*)xp;
            ushort4 o;
            o.x = f2bf(bf2f(old.x) + fmaxf(v[0], 0.f));
            o.y = f2bf(bf2f(old.y) + fmaxf(v[1], 0.f));
            o.z = f2bf(bf2f(old.z) + fmaxf(v[2], 0.f));
            o.w = f2bf(bf2f(old.w) + fmaxf(v[3], 0.f));
            *(ushort4*)xp = o;
        }
    }
}

// ---------------------------------------------------------------------------
// Fused 3-edge masked scores — round-4 proven config (103us): 64x64 tile,
// 2-phase double-buffered, counted vmcnt(4), raw barriers, 32KB LDS.
// ---------------------------------------------------------------------------
__global__ __launch_bounds__(256) void scores_mfma(
    const u16* __restrict__ qb, const u16* __restrict__ kb,
    const int* __restrict__ adj, u16* __restrict__ sb)
{
    __shared__ u16 Qs[2][64 * 64];
    __shared__ u16 Ks[2][64 * 64];

    const int bid = blockIdx.x;
    const int b = bid & 7;
    const int t2 = bid >> 3;
    const int h = t2 & 3;
    const int mt = (t2 >> 2) & 15;
    const int nt = t2 >> 6;
    const int m0 = mt * 64, n0 = nt * 64;
    const int zga = h * 8 + b;

    const int tid = threadIdx.x;
    const int w = tid >> 6, l = tid & 63;
    const int wr = w >> 1, wc = w & 1;
    const int kgrp = l >> 4, lr = l & 15;

    const i64 qoff = ((i64)b * Nv + n0) * Dv + h * DKv;
    const i64 koff = ((i64)b * Nv + m0) * Dv + h * DKv;

#define STAGE_SC(ci_, buf_) { \
    const int e_ = (ci_) / 3, k0_ = ((ci_) % 3) * 64; \
    const u16* qe_ = qb + (i64)e_ * BND + qoff; \
    const u16* ke_ = kb + (i64)e_ * BND + koff; \
    _Pragma("unroll") \
    for (int t = 0; t < 2; ++t) { \
        const int idx2 = t * 256 + tid; \
        const int r = idx2 >> 3, s = idx2 & 7; \
        const int ss = s ^ (r & 7); \
        gl_lds16(qe_ + (i64)r * Dv + k0_ + ss * 8, &Qs[buf_][(t * 256 + w * 64) * 8]); \
        gl_lds16(ke_ + (i64)r * Dv + k0_ + ss * 8, &Ks[buf_][(t * 256 + w * 64) * 8]); \
    } }

    int4 adjv[2][2];
    #pragma unroll
    for (int i = 0; i < 2; ++i) {
        const int mb = m0 + wc * 32 + i * 16 + kgrp * 4;
        #pragma unroll
        for (int j = 0; j < 2; ++j) {
            const int n = n0 + wr * 32 + j * 16 + lr;
            adjv[i][j] = *(const int4*)&adj[((i64)b * Nv + n) * Nv + mb];
        }
    }

    f32x4 acc[3][2][2];
    #pragma unroll
    for (int e = 0; e < 3; ++e)
        #pragma unroll
        for (int i = 0; i < 2; ++i)
            #pragma unroll
            for (int j = 0; j < 2; ++j)
                acc[e][i][j] = (f32x4){0.f, 0.f, 0.f, 0.f};

    STAGE_SC(0, 0)

    #pragma unroll
    for (int ci = 0; ci < 9; ++ci) {
        const int cur = ci & 1;
        if (ci < 8) {
            if (cur) { STAGE_SC(ci + 1, 0) } else { STAGE_SC(ci + 1, 1) }
            VMCNT(4);
        } else {
            VMCNT(0);
        }
        __builtin_amdgcn_s_barrier();
        asm volatile("" ::: "memory");

        const int e = ci / 3;
        #pragma unroll
        for (int ks = 0; ks < 2; ++ks) {
            const int slot = ks * 4 + kgrp;
            short8 a[2], bq2[2];
            #pragma unroll
            for (int i = 0; i < 2; ++i) {
                const int r = wc * 32 + i * 16 + lr;
                a[i] = *(const short8*)&Ks[cur][r * 64 + ((slot ^ (r & 7)) << 3)];
            }
            #pragma unroll
            for (int j = 0; j < 2; ++j) {
                const int r = wr * 32 + j * 16 + lr;
                bq2[j] = *(const short8*)&Qs[cur][r * 64 + ((slot ^ (r & 7)) << 3)];
            }
            #pragma unroll
            for (int i = 0; i < 2; ++i)
                #pragma unroll
                for (int j = 0; j < 2; ++j)
                    acc[e][i][j] = __builtin_amdgcn_mfma_f32_16x16x32_bf16(
                        a[i], bq2[j], acc[e][i][j], 0, 0, 0);
        }

        asm volatile("s_waitcnt lgkmcnt(0)" ::: "memory");
        __builtin_amdgcn_s_barrier();
    }
#undef STAGE_SC

    const float scale = 0.07216878364870323f;  // 1/sqrt(192)
    #pragma unroll
    for (int i = 0; i < 2; ++i) {
        const int mb = m0 + wc * 32 + i * 16 + kgrp * 4;
        #pragma unroll
        for (int j = 0; j < 2; ++j) {
            const int n = n0 + wr * 32 + j * 16 + lr;
            const int av[4] = {adjv[i][j].x, adjv[i][j].y, adjv[i][j].z, adjv[i][j].w};
            ushort4 o;
            #pragma unroll
            for (int rg = 0; rg < 4; ++rg) {
                float f = 0.f;
                if (av[rg] == 1) f = acc[0][i][j][rg];
                else if (av[rg] == 2) f = acc[1][i][j][rg];
                else if (av[rg] == 3) f = acc[2][i][j][rg];
                f *= scale;
                if (f == 0.f) f = -1e9f;
                ((u16*)&o)[rg] = f2bf(f);
            }
            *(ushort4*)&sb[((i64)zga * Nv + n) * Nv + mb] = o;
        }
    }
}

// row softmax over 1024 cols: read S bf16, write ga f32 (output) + P bf16
__global__ __launch_bounds__(256) void softmax_k(const u16* __restrict__ sb,
                                                 float* __restrict__ ga,
                                                 u16* __restrict__ gab)
{
    const i64 row = blockIdx.x;
    const int tid = threadIdx.x;
    const int wid = tid >> 6, lane = tid & 63;

    ushort4 sv = *(const ushort4*)&sb[row * (i64)Nv + tid * 4];
    float4 v;
    v.x = bf2f(sv.x); v.y = bf2f(sv.y); v.z = bf2f(sv.z); v.w = bf2f(sv.w);

    float m = fmaxf(fmaxf(v.x, v.y), fmaxf(v.z, v.w));
    #pragma unroll
    for (int o = 32; o >= 1; o >>= 1) m = fmaxf(m, __shfl_xor(m, o));

    __shared__ float red[4];
    if (lane == 0) red[wid] = m;
    __syncthreads();
    m = fmaxf(fmaxf(red[0], red[1]), fmaxf(red[2], red[3]));

    float e0 = expf(v.x - m), e1 = expf(v.y - m), e2 = expf(v.z - m), e3 = expf(v.w - m);
    float s = e0 + e1 + e2 + e3;
    #pragma unroll
    for (int o = 32; o >= 1; o >>= 1) s += __shfl_xor(s, o);
    __syncthreads();
    if (lane == 0) red[wid] = s;
    __syncthreads();
    s = red[0] + red[1] + red[2] + red[3];

    const float inv = 1.0f / s;
    float4 o;
    o.x = e0 * inv; o.y = e1 * inv; o.z = e2 * inv; o.w = e3 * inv;
    *(float4*)&ga[row * (i64)Nv + tid * 4] = o;

    ushort4 ob;
    ob.x = f2bf(o.x); ob.y = f2bf(o.y); ob.z = f2bf(o.z); ob.w = f2bf(o.w);
    *(ushort4*)&gab[row * (i64)Nv + tid * 4] = ob;
}

// nodes f32 -> nodesb bf16 + X broadcast x4
__global__ __launch_bounds__(256) void prep_k(const float* __restrict__ nodes,
                                              u16* __restrict__ nodesb,
                                              u16* __restrict__ Xb)
{
    const i64 i = (i64)blockIdx.x * 256 + threadIdx.x;
    float4 v = ((const float4*)nodes)[i];
    ushort4 o;
    o.x = f2bf(v.x); o.y = f2bf(v.y); o.z = f2bf(v.z); o.w = f2bf(v.w);
    ((ushort4*)nodesb)[i] = o;
    const i64 q4 = BND / 4;
    #pragma unroll
    for (int h = 0; h < Hh; ++h) ((ushort4*)Xb)[(i64)h * q4 + i] = o;
}

// all weight transposes in one dispatch
__global__ __launch_bounds__(256) void trans_all(
    const float* __restrict__ Wq, const float* __restrict__ Wk,
    const float* __restrict__ gcnW, const float* __restrict__ Wagg,
    u16* __restrict__ wqkt, u16* __restrict__ gcnWt, u16* __restrict__ waggt)
{
    const int z = blockIdx.z;
    const i64 W768 = (i64)768 * 768;
    const float* src;
    u16* dst;
    int ldo;
    if (z < 3)      { src = Wq + z * W768;        dst = wqkt + z * W768;          ldo = 768; }
    else if (z < 6) { src = Wk + (z - 3) * W768;  dst = wqkt + (i64)z * W768;     ldo = 768; }
    else if (z < 8) { src = gcnW + (z - 6) * W768; dst = gcnWt + (i64)(z - 6) * W768; ldo = 768; }
    else            { src = Wagg + (i64)(z - 8) * W768; dst = waggt + (i64)(z - 8) * 768; ldo = 3072; }

    __shared__ u16 t[32][33];
    const int c0 = blockIdx.x * 32, r0 = blockIdx.y * 32;
    const int tx = threadIdx.x & 31, ty = threadIdx.x >> 5;
    #pragma unroll
    for (int i = ty; i < 32; i += 8)
        t[i][tx] = f2bf(src[(i64)(r0 + i) * 768 + c0 + tx]);
    __syncthreads();
    #pragma unroll
    for (int i = ty; i < 32; i += 8)
        dst[(i64)(c0 + i) * ldo + r0 + tx] = t[tx][i];
}

// out = p0 + p1 + bias (split-K reduce)
__global__ __launch_bounds__(256) void addbias_k(
    const float* __restrict__ p0, const float* __restrict__ p1,
    const float* __restrict__ bias, float* __restrict__ out)
{
    const i64 i4 = (i64)blockIdx.x * 256 + threadIdx.x;
    const int nb = (int)((i4 * 4) % Dv);
    float4 a = ((const float4*)p0)[i4];
    float4 b = ((const float4*)p1)[i4];
    float4 bv = *(const float4*)&bias[nb];
    float4 o;
    o.x = a.x + b.x + bv.x; o.y = a.y + b.y + bv.y;
    o.z = a.z + b.z + bv.z; o.w = a.w + b.w + bv.w;
    ((float4*)out)[i4] = o;
}

// ---------------------------------------------------------------------------
extern "C" void kernel_launch(void* const* d_in, const int* in_sizes, int n_in,
                              void* d_out, int out_size, void* d_ws, size_t ws_size,
                              hipStream_t stream)
{
    const float* nodes = (const float*)d_in[0];
    const int*   adj   = (const int*)d_in[1];
    const float* Wq    = (const float*)d_in[2];
    const float* bq    = (const float*)d_in[3];
    const float* Wk    = (const float*)d_in[4];
    const float* bk    = (const float*)d_in[5];
    const float* gcnW  = (const float*)d_in[6];
    const float* gcnb  = (const float*)d_in[7];
    const float* Wagg  = (const float*)d_in[8];
    const float* bagg  = (const float*)d_in[9];

    float* out = (float*)d_out;             // (B,N,D) f32
    float* gaf = out + BND;                 // (H,B,N,N) f32

    const i64 W768 = (i64)768 * 768;
    const i64 HTZ  = (i64)768 * 1024;       // per-z H^T slab [768][1024]
    u16* ws     = (u16*)d_ws;
    u16* qb     = ws;                       // 3*BND           (phase 1)
    u16* kb2    = ws + 3 * BND;             // 3*BND           (phase 1)
    u16* gab    = ws;                       // HBND bf16       (alias after scores)
    u16* nodesb = ws + 6 * BND;             // BND
    u16* gcnWt  = nodesb + BND;             // 2*W768
    u16* waggt  = gcnWt + 2 * W768;         // 4*W768
    u16* Xb     = waggt + 4 * W768;         // HBND
    u16* Htz    = Xb + HBND;                // 32*HTZ, time-shared:
    u16* wqkt   = Htz;                      //   6*W768 (dead after q/k proj)
    u16* sbuf   = Htz;                      //   HBND (S bf16; dead after softmax)
    float* part = (float*)Htz;              //   2*BND f32 (final split-K)

    dim3 blk(256);

    prep_k<<<dim3((unsigned)(BND / 4 / 256)), blk, 0, stream>>>(nodes, nodesb, Xb);
    trans_all<<<dim3(24, 24, 12), blk, 0, stream>>>(Wq, Wk, gcnW, Wagg, wqkt, gcnWt, waggt);

    // fused q/k projections: z 0..2 -> q (bias bq), z 3..5 -> k (bias bk)
    gemm_bf16<1, false, 1, 6, 64, 6><<<dim3(2304), blk, 0, stream>>>(
        nodesb, 0, Dv, wqkt, W768, Dv, -1, bq, Dv, bk, qb, BND, Dv, Dv, 0);

    // fused masked scores -> S bf16 scratch (r4 proven config)
    scores_mfma<<<dim3(8192), blk, 0, stream>>>(qb, kb2, adj, sbuf);

    // softmax: ga f32 (output) + P bf16
    softmax_k<<<dim3(Hh * Bv * Nv), blk, 0, stream>>>(sbuf, gaf, gab);

    for (int it = 0; it < 2; ++it) {
        if (it == 0) {
            // iter 0: per-b H0^T = gcnW[0]^T @ nodes[b]^T; Xupd indexes by z&7
            gemm_bf16<1, false, 0, 8, 6, 8><<<dim3(384), blk, 0, stream>>>(
                gcnWt, 0, Dv, nodesb, (i64)Nv * Dv, Dv, 7, nullptr, 0, nullptr,
                Htz, HTZ, 1024, Dv, 0);
            gemm256_xupd<<<dim3(384), dim3(512), 0, stream>>>(
                gab, (i64)Nv * Nv, Nv, Htz, HTZ, 1024, 7, gcnb,
                Xb, (i64)Nv * Dv, Dv, Nv);
        } else {
            // iter 1: per-z H^T = gcnW[1]^T @ X[z]^T
            gemm_bf16<1, false, 0, 8, 6, 32><<<dim3(1536), blk, 0, stream>>>(
                gcnWt + W768, 0, Dv, Xb, (i64)Nv * Dv, Dv, 31, nullptr, 0, nullptr,
                Htz, HTZ, 1024, Dv, 0);
            gemm256_xupd<<<dim3(384), dim3(512), 0, stream>>>(
                gab, (i64)Nv * Nv, Nv, Htz, HTZ, 1024, 31, gcnb + (i64)Dv,
                Xb, (i64)Nv * Dv, Dv, Nv);
        }
    }

    // final: out = cat(X) @ W_agg + b_agg, split-K x2 into f32 partials
    gemm_bf16<0, true, 0, 6, 64, 2><<<dim3(768), blk, 0, stream>>>(
        Xb, 0, Dv, waggt, 0, Hh * Dv, -1, nullptr, 0, nullptr,
        part, BND, Dv, (Hh * Dv) / 2, (Hh * Dv) / 2);

    addbias_k<<<dim3((unsigned)(BND / 4 / 256)), blk, 0, stream>>>(
        part, part + BND, bagg, out);
}

// Round 12
// 550.479 us; speedup vs baseline: 1.0408x; 1.0295x over previous
//
#include <hip/hip_runtime.h>

typedef long long i64;
typedef unsigned short u16;
typedef __attribute__((ext_vector_type(8))) short short8;
typedef __attribute__((ext_vector_type(4))) float f32x4;

#define Bv 8
#define Nv 1024
#define Dv 768
#define Hh 4
#define DKv 192
#define BND ((i64)Bv * Nv * Dv)      /* 6,291,456  */
#define HBND ((i64)Hh * BND)         /* 25,165,824 */

__device__ __forceinline__ u16 f2bf(float f) {
    unsigned u = __builtin_bit_cast(unsigned, f);
    u += 0x7fffu + ((u >> 16) & 1u);
    return (u16)(u >> 16);
}
__device__ __forceinline__ float bf2f(u16 h) {
    unsigned u = ((unsigned)h) << 16;
    return __builtin_bit_cast(float, u);
}

// async global->LDS, 16B per lane. LDS dest must be wave-uniform base.
__device__ __forceinline__ void gl_lds16(const u16* g, u16* l) {
    __builtin_amdgcn_global_load_lds(
        (const __attribute__((address_space(1))) void*)g,
        (__attribute__((address_space(3))) void*)l, 16, 0, 0);
}

// ---------------------------------------------------------------------------
// bf16 MFMA GEMM (m97-structure): 128x128 tile, BK=64, 256 threads, ~790 TF.
// (unchanged from round 7 — see comments there)
// ---------------------------------------------------------------------------
template <int EPI, bool CATK, int ORD, int NBN, int NBM, int NZ>
__global__ __launch_bounds__(256) void gemm_bf16(
    const u16* __restrict__ A, i64 sA, int lda,
    const u16* __restrict__ Bt, i64 sBt, int ldbt, int zmaskBt,
    const float* __restrict__ bias, i64 sBias, const float* __restrict__ bias2,
    void* __restrict__ Cv, i64 sC, int ldc, int K, int koff)
{
    __shared__ u16 Asb[128 * 64];
    __shared__ u16 Bsb[128 * 64];

    const int L = (blockIdx.x & 7) * ((NBN * NBM * NZ) >> 3) + (blockIdx.x >> 3);
    int bn, bm, z;
    if (ORD == 0) {
        bn = L % NBN; const int t2 = L / NBN; bm = t2 % NBM; z = t2 / NBM;
    } else {
        bn = L % NBN; const int t2 = L / NBN; z = t2 % NZ; bm = t2 / NZ;
    }

    A  += (i64)z * sA;
    Bt += (i64)(z & zmaskBt) * sBt;
    const float* bp = bias;
    int zb = z;
    if (bias2 != nullptr && z >= NZ / 2) { bp = bias2; zb = z - NZ / 2; }
    if (bp) bp += (i64)zb * sBias;
    const int kb = z * koff;

    const int bmp = bm * 128, bnp = bn * 128;
    const int tid = threadIdx.x;
    const int w = tid >> 6, l = tid & 63;
    const int wr = w >> 1, wc = w & 1;
    const int kgrp = l >> 4, lr = l & 15;

    const u16* Ab = A + (i64)bmp * lda;
    const u16* Bb = Bt + (i64)bnp * ldbt;

    f32x4 acc[4][4];
    #pragma unroll
    for (int i = 0; i < 4; ++i)
        #pragma unroll
        for (int j = 0; j < 4; ++j)
            acc[i][j] = (f32x4){0.f, 0.f, 0.f, 0.f};

    for (int k0i = 0; k0i < K; k0i += 64) {
        const int k0 = kb + k0i;
        if (k0i) __syncthreads();
        #pragma unroll
        for (int t = 0; t < 4; ++t) {
            const int idx = t * 256 + tid;
            const int r = idx >> 3, s = idx & 7;
            const int ss = s ^ (r & 7);
            const u16* src;
            if (CATK) {
                src = A + (i64)(k0 / Dv) * BND + (i64)(bmp + r) * Dv + (k0 % Dv) + ss * 8;
            } else {
                src = Ab + (i64)r * lda + k0 + ss * 8;
            }
            gl_lds16(src, &Asb[(t * 256 + w * 64) * 8]);
        }
        #pragma unroll
        for (int t = 0; t < 4; ++t) {
            const int idx = t * 256 + tid;
            const int r = idx >> 3, s = idx & 7;
            const int ss = s ^ (r & 7);
            gl_lds16(Bb + (i64)r * ldbt + k0 + ss * 8, &Bsb[(t * 256 + w * 64) * 8]);
        }
        __syncthreads();

        #pragma unroll
        for (int ks = 0; ks < 2; ++ks) {
            const int slot = ks * 4 + kgrp;
            short8 a[4], b[4];
            #pragma unroll
            for (int i = 0; i < 4; ++i) {
                const int r = wc * 64 + i * 16 + lr;
                a[i] = *(const short8*)&Bsb[r * 64 + ((slot ^ (r & 7)) << 3)];
            }
            #pragma unroll
            for (int j = 0; j < 4; ++j) {
                const int r = wr * 64 + j * 16 + lr;
                b[j] = *(const short8*)&Asb[r * 64 + ((slot ^ (r & 7)) << 3)];
            }
            #pragma unroll
            for (int i = 0; i < 4; ++i)
                #pragma unroll
                for (int j = 0; j < 4; ++j)
                    acc[i][j] = __builtin_amdgcn_mfma_f32_16x16x32_bf16(
                        a[i], b[j], acc[i][j], 0, 0, 0);
        }
    }

    f32x4 bj[4];
    #pragma unroll
    for (int i = 0; i < 4; ++i) {
        const int nb = bnp + wc * 64 + i * 16 + kgrp * 4;
        bj[i] = bp ? *(const f32x4*)&bp[nb] : (f32x4){0.f, 0.f, 0.f, 0.f};
    }

    #pragma unroll
    for (int j = 0; j < 4; ++j) {
        const int m = bmp + wr * 64 + j * 16 + lr;
        #pragma unroll
        for (int i = 0; i < 4; ++i) {
            const int nb = bnp + wc * 64 + i * 16 + kgrp * 4;
            const i64 off = (i64)z * sC + (i64)m * ldc + nb;
            f32x4 v = acc[i][j] + bj[i];
            if (EPI == 0) {
                *(f32x4*)&((float*)Cv)[off] = v;
            } else if (EPI == 1) {
                ushort4 o;
                o.x = f2bf(v[0]); o.y = f2bf(v[1]);
                o.z = f2bf(v[2]); o.w = f2bf(v[3]);
                *(ushort4*)&((u16*)Cv)[off] = o;
            } else {
                u16* xp = (u16*)Cv + off;
                ushort4 old = *(const ushort4*)xp;
                ushort4 o;
                o.x = f2bf(bf2f(old.x) + fmaxf(v[0], 0.f));
                o.y = f2bf(bf2f(old.y) + fmaxf(v[1], 0.f));
                o.z = f2bf(bf2f(old.z) + fmaxf(v[2], 0.f));
                o.w = f2bf(bf2f(old.w) + fmaxf(v[3], 0.f));
                *(ushort4*)xp = o;
            }
        }
    }
}

// ---------------------------------------------------------------------------
// Fused 3-edge masked scores, 128x128 tile, fin-in-LDS.
// Loop structure IDENTICAL to gemm_bf16 (single-buffered, 2-barrier, 32 MFMA
// per K-chunk per wave — the proven ~790 TF density). Edges sequential,
// reusing one acc[4][4]; after each edge's K-loop, fold into LDS fin via
// adj-select. fin layout is THREAD-PRIVATE interleaved ushort2: pair p of
// thread t lives at u32 index p*256+t (4B lane stride -> conflict-free).
// Final pass: (fin&0x7fff)==0 -> -1e9, vectorized ushort4 store (one clean
// 66MB write — fixes r10's 243MB write-allocate blowup).
// LDS 16+16+32 = 64 KB -> 2 blocks/CU. VGPR ~= gemm's (no fin/adj in regs).
// Grid 2048: b = bid&7 (XCD pin), h fastest, then 8x8 tiles of 128.
// ---------------------------------------------------------------------------
__global__ __launch_bounds__(256) void scores_mfma(
    const u16* __restrict__ qb, const u16* __restrict__ kb,
    const int* __restrict__ adj, u16* __restrict__ sb)
{
    __shared__ u16 Qs[128 * 64];          // 16 KB
    __shared__ u16 Ks[128 * 64];          // 16 KB
    __shared__ unsigned fin32[32 * 256];  // 32 KB: pair p of thread t at p*256+t

    const int bid = blockIdx.x;
    const int b = bid & 7;
    const int t2 = bid >> 3;          // [0,256)
    const int h = t2 & 3;
    const int tile = t2 >> 2;         // [0,64)
    const int mt = tile & 7, nt = tile >> 3;
    const int m0 = mt * 128, n0 = nt * 128;
    const int zga = h * 8 + b;

    const int tid = threadIdx.x;
    const int w = tid >> 6, l = tid & 63;
    const int wr = w >> 1, wc = w & 1;   // wr: n-half, wc: m-half
    const int kgrp = l >> 4, lr = l & 15;

    const u16* qbase = qb + ((i64)b * Nv + n0) * Dv + h * DKv;
    const u16* kbase = kb + ((i64)b * Nv + m0) * Dv + h * DKv;

    const float scale = 0.07216878364870323f;  // 1/sqrt(192)
    const u16 NEG = f2bf(-1e9f);

    for (int e = 0; e < 3; ++e) {
        const u16* qe = qbase + (i64)e * BND;
        const u16* ke = kbase + (i64)e * BND;

        f32x4 acc[4][4];   // [i: m-frag (reg dim)][j: n-frag (lane dim)]
        #pragma unroll
        for (int i = 0; i < 4; ++i)
            #pragma unroll
            for (int j = 0; j < 4; ++j)
                acc[i][j] = (f32x4){0.f, 0.f, 0.f, 0.f};

        for (int k0 = 0; k0 < DKv; k0 += 64) {
            __syncthreads();   // protect Qs/Ks vs previous chunk's readers
            #pragma unroll
            for (int t = 0; t < 4; ++t) {
                const int idx = t * 256 + tid;
                const int r = idx >> 3, s = idx & 7;
                const int ss = s ^ (r & 7);
                gl_lds16(qe + (i64)r * Dv + k0 + ss * 8, &Qs[(t * 256 + w * 64) * 8]);
            }
            #pragma unroll
            for (int t = 0; t < 4; ++t) {
                const int idx = t * 256 + tid;
                const int r = idx >> 3, s = idx & 7;
                const int ss = s ^ (r & 7);
                gl_lds16(ke + (i64)r * Dv + k0 + ss * 8, &Ks[(t * 256 + w * 64) * 8]);
            }
            __syncthreads();

            #pragma unroll
            for (int ks = 0; ks < 2; ++ks) {
                const int slot = ks * 4 + kgrp;
                short8 a[4], bq2[4];
                #pragma unroll
                for (int i = 0; i < 4; ++i) {          // K rows (m side, reg dim)
                    const int r = wc * 64 + i * 16 + lr;
                    a[i] = *(const short8*)&Ks[r * 64 + ((slot ^ (r & 7)) << 3)];
                }
                #pragma unroll
                for (int j = 0; j < 4; ++j) {          // Q rows (n side, lane dim)
                    const int r = wr * 64 + j * 16 + lr;
                    bq2[j] = *(const short8*)&Qs[r * 64 + ((slot ^ (r & 7)) << 3)];
                }
                #pragma unroll
                for (int i = 0; i < 4; ++i)
                    #pragma unroll
                    for (int j = 0; j < 4; ++j)
                        acc[i][j] = __builtin_amdgcn_mfma_f32_16x16x32_bf16(
                            a[i], bq2[j], acc[i][j], 0, 0, 0);
            }
        }

        // fold edge e into thread-private LDS fin (no barrier needed: each
        // fin slot is read/written by exactly one thread, program order)
        #pragma unroll
        for (int i = 0; i < 4; ++i) {
            const int mb = m0 + wc * 64 + i * 16 + kgrp * 4;
            #pragma unroll
            for (int j = 0; j < 4; ++j) {
                const int n = n0 + wr * 64 + j * 16 + lr;
                const int4 av = *(const int4*)&adj[((i64)b * Nv + n) * Nv + mb];
                const int avv[4] = {av.x, av.y, av.z, av.w};
                const int pbase = (i * 4 + j) * 2;
                #pragma unroll
                for (int pp = 0; pp < 2; ++pp) {
                    unsigned cur = (e == 0) ? 0u : fin32[(pbase + pp) * 256 + tid];
                    u16 lo = (u16)(cur & 0xffffu), hi = (u16)(cur >> 16);
                    if (avv[pp * 2 + 0] == e + 1) lo = f2bf(acc[i][j][pp * 2 + 0] * scale);
                    if (avv[pp * 2 + 1] == e + 1) hi = f2bf(acc[i][j][pp * 2 + 1] * scale);
                    fin32[(pbase + pp) * 256 + tid] = (unsigned)lo | ((unsigned)hi << 16);
                }
            }
        }
    }

    // final: fin==+-0 -> -1e9, vectorized store
    #pragma unroll
    for (int i = 0; i < 4; ++i) {
        const int mb = m0 + wc * 64 + i * 16 + kgrp * 4;
        #pragma unroll
        for (int j = 0; j < 4; ++j) {
            const int n = n0 + wr * 64 + j * 16 + lr;
            const int pbase = (i * 4 + j) * 2;
            ushort4 o;
            #pragma unroll
            for (int pp = 0; pp < 2; ++pp) {
                const unsigned cur = fin32[(pbase + pp) * 256 + tid];
                u16 lo = (u16)(cur & 0xffffu), hi = (u16)(cur >> 16);
                if ((lo & 0x7fffu) == 0) lo = NEG;
                if ((hi & 0x7fffu) == 0) hi = NEG;
                ((u16*)&o)[pp * 2 + 0] = lo;
                ((u16*)&o)[pp * 2 + 1] = hi;
            }
            *(ushort4*)&sb[((i64)zga * Nv + n) * Nv + mb] = o;
        }
    }
}

// row softmax over 1024 cols: read S bf16, write ga f32 (output) + P bf16
__global__ __launch_bounds__(256) void softmax_k(const u16* __restrict__ sb,
                                                 float* __restrict__ ga,
                                                 u16* __restrict__ gab)
{
    const i64 row = blockIdx.x;
    const int tid = threadIdx.x;
    const int wid = tid >> 6, lane = tid & 63;

    ushort4 sv = *(const ushort4*)&sb[row * (i64)Nv + tid * 4];
    float4 v;
    v.x = bf2f(sv.x); v.y = bf2f(sv.y); v.z = bf2f(sv.z); v.w = bf2f(sv.w);

    float m = fmaxf(fmaxf(v.x, v.y), fmaxf(v.z, v.w));
    #pragma unroll
    for (int o = 32; o >= 1; o >>= 1) m = fmaxf(m, __shfl_xor(m, o));

    __shared__ float red[4];
    if (lane == 0) red[wid] = m;
    __syncthreads();
    m = fmaxf(fmaxf(red[0], red[1]), fmaxf(red[2], red[3]));

    float e0 = expf(v.x - m), e1 = expf(v.y - m), e2 = expf(v.z - m), e3 = expf(v.w - m);
    float s = e0 + e1 + e2 + e3;
    #pragma unroll
    for (int o = 32; o >= 1; o >>= 1) s += __shfl_xor(s, o);
    __syncthreads();
    if (lane == 0) red[wid] = s;
    __syncthreads();
    s = red[0] + red[1] + red[2] + red[3];

    const float inv = 1.0f / s;
    float4 o;
    o.x = e0 * inv; o.y = e1 * inv; o.z = e2 * inv; o.w = e3 * inv;
    *(float4*)&ga[row * (i64)Nv + tid * 4] = o;

    ushort4 ob;
    ob.x = f2bf(o.x); ob.y = f2bf(o.y); ob.z = f2bf(o.z); ob.w = f2bf(o.w);
    *(ushort4*)&gab[row * (i64)Nv + tid * 4] = ob;
}

// nodes f32 -> nodesb bf16 + X broadcast x4
__global__ __launch_bounds__(256) void prep_k(const float* __restrict__ nodes,
                                              u16* __restrict__ nodesb,
                                              u16* __restrict__ Xb)
{
    const i64 i = (i64)blockIdx.x * 256 + threadIdx.x;
    float4 v = ((const float4*)nodes)[i];
    ushort4 o;
    o.x = f2bf(v.x); o.y = f2bf(v.y); o.z = f2bf(v.z); o.w = f2bf(v.w);
    ((ushort4*)nodesb)[i] = o;
    const i64 q4 = BND / 4;
    #pragma unroll
    for (int h = 0; h < Hh; ++h) ((ushort4*)Xb)[(i64)h * q4 + i] = o;
}

// all weight transposes in one dispatch
__global__ __launch_bounds__(256) void trans_all(
    const float* __restrict__ Wq, const float* __restrict__ Wk,
    const float* __restrict__ gcnW, const float* __restrict__ Wagg,
    u16* __restrict__ wqkt, u16* __restrict__ gcnWt, u16* __restrict__ waggt)
{
    const int z = blockIdx.z;
    const i64 W768 = (i64)768 * 768;
    const float* src;
    u16* dst;
    int ldo;
    if (z < 3)      { src = Wq + z * W768;        dst = wqkt + z * W768;          ldo = 768; }
    else if (z < 6) { src = Wk + (z - 3) * W768;  dst = wqkt + (i64)z * W768;     ldo = 768; }
    else if (z < 8) { src = gcnW + (z - 6) * W768; dst = gcnWt + (i64)(z - 6) * W768; ldo = 768; }
    else            { src = Wagg + (i64)(z - 8) * W768; dst = waggt + (i64)(z - 8) * 768; ldo = 3072; }

    __shared__ u16 t[32][33];
    const int c0 = blockIdx.x * 32, r0 = blockIdx.y * 32;
    const int tx = threadIdx.x & 31, ty = threadIdx.x >> 5;
    #pragma unroll
    for (int i = ty; i < 32; i += 8)
        t[i][tx] = f2bf(src[(i64)(r0 + i) * 768 + c0 + tx]);
    __syncthreads();
    #pragma unroll
    for (int i = ty; i < 32; i += 8)
        dst[(i64)(c0 + i) * ldo + r0 + tx] = t[tx][i];
}

// out = p0 + p1 + bias (split-K reduce)
__global__ __launch_bounds__(256) void addbias_k(
    const float* __restrict__ p0, const float* __restrict__ p1,
    const float* __restrict__ bias, float* __restrict__ out)
{
    const i64 i4 = (i64)blockIdx.x * 256 + threadIdx.x;
    const int nb = (int)((i4 * 4) % Dv);
    float4 a = ((const float4*)p0)[i4];
    float4 b = ((const float4*)p1)[i4];
    float4 bv = *(const float4*)&bias[nb];
    float4 o;
    o.x = a.x + b.x + bv.x; o.y = a.y + b.y + bv.y;
    o.z = a.z + b.z + bv.z; o.w = a.w + b.w + bv.w;
    ((float4*)out)[i4] = o;
}

// ---------------------------------------------------------------------------
extern "C" void kernel_launch(void* const* d_in, const int* in_sizes, int n_in,
                              void* d_out, int out_size, void* d_ws, size_t ws_size,
                              hipStream_t stream)
{
    const float* nodes = (const float*)d_in[0];
    const int*   adj   = (const int*)d_in[1];
    const float* Wq    = (const float*)d_in[2];
    const float* bq    = (const float*)d_in[3];
    const float* Wk    = (const float*)d_in[4];
    const float* bk    = (const float*)d_in[5];
    const float* gcnW  = (const float*)d_in[6];
    const float* gcnb  = (const float*)d_in[7];
    const float* Wagg  = (const float*)d_in[8];
    const float* bagg  = (const float*)d_in[9];

    float* out = (float*)d_out;             // (B,N,D) f32
    float* gaf = out + BND;                 // (H,B,N,N) f32

    const i64 W768 = (i64)768 * 768;
    const i64 HTZ  = (i64)768 * 1024;       // per-z H^T slab [768][1024]
    u16* ws     = (u16*)d_ws;
    u16* qb     = ws;                       // 3*BND           (phase 1)
    u16* kb2    = ws + 3 * BND;             // 3*BND           (phase 1)
    u16* gab    = ws;                       // HBND bf16       (alias after scores)
    u16* nodesb = ws + 6 * BND;             // BND
    u16* gcnWt  = nodesb + BND;             // 2*W768
    u16* waggt  = gcnWt + 2 * W768;         // 4*W768
    u16* Xb     = waggt + 4 * W768;         // HBND
    u16* Htz    = Xb + HBND;                // 32*HTZ, time-shared:
    u16* wqkt   = Htz;                      //   6*W768 (dead after q/k proj)
    u16* sbuf   = Htz;                      //   HBND (S bf16; dead after softmax)
    float* part = (float*)Htz;              //   2*BND f32 (final split-K)

    dim3 blk(256);

    prep_k<<<dim3((unsigned)(BND / 4 / 256)), blk, 0, stream>>>(nodes, nodesb, Xb);
    trans_all<<<dim3(24, 24, 12), blk, 0, stream>>>(Wq, Wk, gcnW, Wagg, wqkt, gcnWt, waggt);

    // fused q/k projections: z 0..2 -> q (bias bq), z 3..5 -> k (bias bk)
    gemm_bf16<1, false, 1, 6, 64, 6><<<dim3(2304), blk, 0, stream>>>(
        nodesb, 0, Dv, wqkt, W768, Dv, -1, bq, Dv, bk, qb, BND, Dv, Dv, 0);

    // fused masked scores -> S bf16 (128x128 tiles, fin-in-LDS)
    scores_mfma<<<dim3(2048), blk, 0, stream>>>(qb, kb2, adj, sbuf);

    // softmax: ga f32 (output) + P bf16
    softmax_k<<<dim3(Hh * Bv * Nv), blk, 0, stream>>>(sbuf, gaf, gab);

    for (int it = 0; it < 2; ++it) {
        if (it == 0) {
            // iter 0: per-b H0^T = gcnW[0]^T @ nodes[b]^T; Xupd indexes by z&7
            gemm_bf16<1, false, 0, 8, 6, 8><<<dim3(384), blk, 0, stream>>>(
                gcnWt, 0, Dv, nodesb, (i64)Nv * Dv, Dv, 7, nullptr, 0, nullptr,
                Htz, HTZ, 1024, Dv, 0);
            gemm_bf16<2, false, 0, 6, 8, 32><<<dim3(1536), blk, 0, stream>>>(
                gab, (i64)Nv * Nv, Nv, Htz, HTZ, 1024, 7, gcnb, 0, nullptr,
                Xb, (i64)Nv * Dv, Dv, Nv, 0);
        } else {
            // iter 1: per-z H^T = gcnW[1]^T @ X[z]^T
            gemm_bf16<1, false, 0, 8, 6, 32><<<dim3(1536), blk, 0, stream>>>(
                gcnWt + W768, 0, Dv, Xb, (i64)Nv * Dv, Dv, 31, nullptr, 0, nullptr,
                Htz, HTZ, 1024, Dv, 0);
            gemm_bf16<2, false, 0, 6, 8, 32><<<dim3(1536), blk, 0, stream>>>(
                gab, (i64)Nv * Nv, Nv, Htz, HTZ, 1024, 31, gcnb + (i64)Dv, 0, nullptr,
                Xb, (i64)Nv * Dv, Dv, Nv, 0);
        }
    }

    // final: out = cat(X) @ W_agg + b_agg, split-K x2 into f32 partials
    gemm_bf16<0, true, 0, 6, 64, 2><<<dim3(768), blk, 0, stream>>>(
        Xb, 0, Dv, waggt, 0, Hh * Dv, -1, nullptr, 0, nullptr,
        part, BND, Dv, (Hh * Dv) / 2, (Hh * Dv) / 2);

    addbias_k<<<dim3((unsigned)(BND / 4 / 256)), blk, 0, stream>>>(
        part, part + BND, bagg, out);
}